// Round 4
// baseline (5445.398 us; speedup 1.0000x reference)
//
#include <hip/hip_runtime.h>

#define BB 512
#define TT 2048
#define DD 8
#define HH 64

// LDS layout (bytes), all 16B-aligned:
//   wAB  : float2[256][66]  @ 0       (135168)  (wih1[g][k], whh0[g][k]), stride 66 -> even => b128-merge ok, banks balanced
//   g0act: float2[256]      @ 135168  (2048)
//   g1act: float2[256]      @ 137216  (2048)
//   h0p  : float2[64]       @ 139264  (512)
//   h1p  : float2[64]       @ 139776  (512)
#define LDS_BYTES 140288
#define WSTRIDE 66

__device__ __forceinline__ float sigm(float x) { return 1.0f / (1.0f + __expf(-x)); }
__device__ __forceinline__ float tanh_fast(float x) { return 1.0f - 2.0f / (__expf(2.0f * x) + 1.0f); }
__device__ __forceinline__ float2 f2fma(float s, float2 v, float2 a) {
  a.x = fmaf(s, v.x, a.x); a.y = fmaf(s, v.y, a.y); return a;
}

// One block per CU (LDS-forced). Block bb owns batches (2bb, 2bb+1).
// Thread g in [0,256) owns gate row g of both layers for BOTH batches;
// accumulators/state are float2 packed (batchA, batchB).
// Weights wih1/whh0 live in LDS (structural residency — round 1-3 failure was
// per-thread weight arrays demoted to L1/L2-reloaded allocas, ~5k cy/step);
// whh1 (64) + wih0 (8) are macro-NAMED scalars (no alloca => no demotion).
// h state is broadcast via uniform-address ds_read_b128 from tiny LDS arrays.
__global__ void __launch_bounds__(256) lstm2_fused(
    const float* __restrict__ x,
    const float* __restrict__ w_ih0, const float* __restrict__ w_hh0,
    const float* __restrict__ b_ih0, const float* __restrict__ b_hh0,
    const float* __restrict__ w_ih1, const float* __restrict__ w_hh1,
    const float* __restrict__ b_ih1, const float* __restrict__ b_hh1,
    const float* __restrict__ w_out, const float* __restrict__ b_out,
    float* __restrict__ out)
{
  extern __shared__ char smem[];
  float2* const wAB   = (float2*)(smem);
  float2* const g0act = (float2*)(smem + 135168);
  float2* const g1act = (float2*)(smem + 137216);
  float2* const h0p   = (float2*)(smem + 139264);
  float2* const h1p   = (float2*)(smem + 139776);

  const int bb  = blockIdx.x;
  const int g   = threadIdx.x;       // gate row 0..255
  const int ln  = g & 63;            // this thread's state element
  const bool is_tanh = ((g >> 6) == 2);  // gate order i,f,g,o

  // ---- one-time: stage (wih1, whh0) into LDS, coalesced ----
  for (int i = g; i < 256 * 64; i += 256) {
    const int gate = i >> 6, k = i & 63;
    wAB[gate * WSTRIDE + k] = make_float2(w_ih1[i], w_hh0[i]);
  }
  if (g < 64) { h0p[g] = make_float2(0.f, 0.f); h1p[g] = make_float2(0.f, 0.f); }

  // ---- one-time: whh1 row + wih0 row as NAMED scalars (no alloca) ----
  const float* w11r = w_hh1 + g * HH;
  const float* wxr  = w_ih0 + g * DD;
#define DW(i) const float w11_##i = w11r[i];
  DW(0) DW(1) DW(2) DW(3) DW(4) DW(5) DW(6) DW(7)
  DW(8) DW(9) DW(10) DW(11) DW(12) DW(13) DW(14) DW(15)
  DW(16) DW(17) DW(18) DW(19) DW(20) DW(21) DW(22) DW(23)
  DW(24) DW(25) DW(26) DW(27) DW(28) DW(29) DW(30) DW(31)
  DW(32) DW(33) DW(34) DW(35) DW(36) DW(37) DW(38) DW(39)
  DW(40) DW(41) DW(42) DW(43) DW(44) DW(45) DW(46) DW(47)
  DW(48) DW(49) DW(50) DW(51) DW(52) DW(53) DW(54) DW(55)
  DW(56) DW(57) DW(58) DW(59) DW(60) DW(61) DW(62) DW(63)
#undef DW
  const float wx_0 = wxr[0], wx_1 = wxr[1], wx_2 = wxr[2], wx_3 = wxr[3];
  const float wx_4 = wxr[4], wx_5 = wxr[5], wx_6 = wxr[6], wx_7 = wxr[7];

  const float bias0 = b_ih0[g] + b_hh0[g];
  const float bias1 = b_ih1[g] + b_hh1[g];

  // state (packed over the batch pair), per-thread for its lane 'ln'
  float2 c0 = make_float2(0.f, 0.f), c1 = make_float2(0.f, 0.f);
  // carried layer-0 preactivation: bias0 + Whh0 . h0(t-1)
  float2 acc0 = make_float2(bias0, bias0);

  const float* xA = x + (size_t)(2 * bb) * TT * DD;
  const float* xB = xA + (size_t)TT * DD;
  float4 xa0 = *(const float4*)(xA), xa1 = *(const float4*)(xA + 4);
  float4 xb0 = *(const float4*)(xB), xb1 = *(const float4*)(xB + 4);

  const float2* const wABg = wAB + g * WSTRIDE;

  __syncthreads();  // weights + h1p init visible

  for (int t = 0; t < TT; ++t) {
    // ---- phase A: finish layer-0 preact with x(t); activate; publish ----
    acc0 = f2fma(wx_0, make_float2(xa0.x, xb0.x), acc0);
    acc0 = f2fma(wx_1, make_float2(xa0.y, xb0.y), acc0);
    acc0 = f2fma(wx_2, make_float2(xa0.z, xb0.z), acc0);
    acc0 = f2fma(wx_3, make_float2(xa0.w, xb0.w), acc0);
    acc0 = f2fma(wx_4, make_float2(xa1.x, xb1.x), acc0);
    acc0 = f2fma(wx_5, make_float2(xa1.y, xb1.y), acc0);
    acc0 = f2fma(wx_6, make_float2(xa1.z, xb1.z), acc0);
    acc0 = f2fma(wx_7, make_float2(xa1.w, xb1.w), acc0);
    {
      float2 a0;
      if (is_tanh) { a0.x = tanh_fast(acc0.x); a0.y = tanh_fast(acc0.y); }
      else         { a0.x = sigm(acc0.x);      a0.y = sigm(acc0.y); }
      g0act[g] = a0;
    }
    __syncthreads();  // bar1

    // prefetch x(t+1) — consumed next iteration
    {
      const int tn = (t + 1 < TT) ? (t + 1) : (TT - 1);
      xa0 = *(const float4*)(xA + tn * DD);
      xa1 = *(const float4*)(xA + tn * DD + 4);
      xb0 = *(const float4*)(xB + tn * DD);
      xb1 = *(const float4*)(xB + tn * DD + 4);
    }

    // ---- upd0: layer-0 cell update for lane 'ln' (replicated per wave) ----
    {
      const float2 ip = g0act[ln], fp = g0act[64 + ln];
      const float2 gp = g0act[128 + ln], op = g0act[192 + ln];
      c0.x = fmaf(fp.x, c0.x, ip.x * gp.x);
      c0.y = fmaf(fp.y, c0.y, ip.y * gp.y);
      float2 h0;
      h0.x = op.x * tanh_fast(c0.x);
      h0.y = op.y * tanh_fast(c0.y);
      if (g < 64) h0p[g] = h0;
    }
    __syncthreads();  // bar2: h0p(t) visible

    // ---- phase C: layer-1 preact (wih1.h0 + whh1.h1) and next-step whh0.h0 ----
    float2 acc1  = make_float2(bias1, bias1);
    float2 acc0n = make_float2(bias0, bias0);
#define KS(ka, kb)                                              \
    {                                                           \
      const float4 hq0 = *(const float4*)(h0p + (ka));          \
      const float4 hq1 = *(const float4*)(h1p + (ka));          \
      const float2 wa = wABg[(ka)];                             \
      const float2 wb = wABg[(kb)];                             \
      acc1  = f2fma(wa.x, make_float2(hq0.x, hq0.y), acc1);     \
      acc0n = f2fma(wa.y, make_float2(hq0.x, hq0.y), acc0n);    \
      acc1  = f2fma(w11_##ka, make_float2(hq1.x, hq1.y), acc1); \
      acc1  = f2fma(wb.x, make_float2(hq0.z, hq0.w), acc1);     \
      acc0n = f2fma(wb.y, make_float2(hq0.z, hq0.w), acc0n);    \
      acc1  = f2fma(w11_##kb, make_float2(hq1.z, hq1.w), acc1); \
    }
    KS(0, 1)   KS(2, 3)   KS(4, 5)   KS(6, 7)
    KS(8, 9)   KS(10, 11) KS(12, 13) KS(14, 15)
    KS(16, 17) KS(18, 19) KS(20, 21) KS(22, 23)
    KS(24, 25) KS(26, 27) KS(28, 29) KS(30, 31)
    KS(32, 33) KS(34, 35) KS(36, 37) KS(38, 39)
    KS(40, 41) KS(42, 43) KS(44, 45) KS(46, 47)
    KS(48, 49) KS(50, 51) KS(52, 53) KS(54, 55)
    KS(56, 57) KS(58, 59) KS(60, 61) KS(62, 63)
#undef KS
    {
      float2 a1;
      if (is_tanh) { a1.x = tanh_fast(acc1.x); a1.y = tanh_fast(acc1.y); }
      else         { a1.x = sigm(acc1.x);      a1.y = sigm(acc1.y); }
      g1act[g] = a1;
    }
    acc0 = acc0n;
    __syncthreads();  // bar3

    // ---- upd1: layer-1 cell update; publish h1(t) for next step ----
    {
      const float2 ip = g1act[ln], fp = g1act[64 + ln];
      const float2 gp = g1act[128 + ln], op = g1act[192 + ln];
      c1.x = fmaf(fp.x, c1.x, ip.x * gp.x);
      c1.y = fmaf(fp.y, c1.y, ip.y * gp.y);
      float2 h1;
      h1.x = op.x * tanh_fast(c1.x);
      h1.y = op.y * tanh_fast(c1.y);
      if (g < 64) h1p[g] = h1;
      if (t == TT - 1 && g < 64) {
        // head: out[b] = dot(h1, w_out) + b_out, reduced on wave 0
        float vA = h1.x * w_out[g];
        float vB = h1.y * w_out[g];
#pragma unroll
        for (int off = 32; off; off >>= 1) {
          vA += __shfl_down(vA, off);
          vB += __shfl_down(vB, off);
        }
        if (g == 0) {
          out[2 * bb]     = vA + b_out[0];
          out[2 * bb + 1] = vB + b_out[0];
        }
      }
    }
  }
}

extern "C" void kernel_launch(void* const* d_in, const int* in_sizes, int n_in,
                              void* d_out, int out_size, void* d_ws, size_t ws_size,
                              hipStream_t stream) {
  const float* x     = (const float*)d_in[0];
  const float* w_ih0 = (const float*)d_in[1];
  const float* w_hh0 = (const float*)d_in[2];
  const float* b_ih0 = (const float*)d_in[3];
  const float* b_hh0 = (const float*)d_in[4];
  const float* w_ih1 = (const float*)d_in[5];
  const float* w_hh1 = (const float*)d_in[6];
  const float* b_ih1 = (const float*)d_in[7];
  const float* b_hh1 = (const float*)d_in[8];
  const float* w_out = (const float*)d_in[9];
  const float* b_out = (const float*)d_in[10];
  float* out = (float*)d_out;

  // allow >64KB dynamic LDS (gfx950 has 160 KiB/CU); harmless if redundant
  (void)hipFuncSetAttribute((const void*)lstm2_fused,
                            hipFuncAttributeMaxDynamicSharedMemorySize, LDS_BYTES);

  lstm2_fused<<<dim3(256), dim3(256), LDS_BYTES, stream>>>(
      x, w_ih0, w_hh0, b_ih0, b_hh0,
      w_ih1, w_hh1, b_ih1, b_hh1,
      w_out, b_out, out);
}